// Round 8
// baseline (438.195 us; speedup 1.0000x reference)
//
#include <hip/hip_runtime.h>
#include <stdint.h>

#define K_DIM 4096
#define N_DIM 11008
#define NCOL  1376   // N/8

typedef __attribute__((ext_vector_type(4))) float  f32x4;
typedef __attribute__((ext_vector_type(8))) __bf16 bf16x8;

__device__ __forceinline__ void gload_lds16(const void* g, void* l) {
  __builtin_amdgcn_global_load_lds((const __attribute__((address_space(1))) void*)g,
                                   (__attribute__((address_space(3))) void*)l,
                                   16, 0, 0);
}

// ---------- prologue 1: x fp32 -> bf16 ----------
__global__ void __launch_bounds__(256) convert_x_kernel(const float* __restrict__ x,
                                                        __bf16* __restrict__ a) {
  size_t i = ((size_t)blockIdx.x * 256u + threadIdx.x) * 8u;
  f32x4 v0 = *(const f32x4*)(x + i);
  f32x4 v1 = *(const f32x4*)(x + i + 4);
  bf16x8 o;
  o[0] = (__bf16)v0[0]; o[1] = (__bf16)v0[1]; o[2] = (__bf16)v0[2]; o[3] = (__bf16)v0[3];
  o[4] = (__bf16)v1[0]; o[5] = (__bf16)v1[1]; o[6] = (__bf16)v1[2]; o[7] = (__bf16)v1[3];
  *(bf16x8*)(a + i) = o;
}

// ---------- prologue 2: AWQ dequant -> Wt bf16 [N][K] (transposed via LDS) ----------
__global__ void __launch_bounds__(256) dequant_kernel(const int* __restrict__ qw,
                                                      const int* __restrict__ qz,
                                                      const float* __restrict__ sc,
                                                      __bf16* __restrict__ wt) {
  constexpr int SH[8] = {0, 16, 4, 20, 8, 24, 12, 28};  // AWQ [0,4,1,5,2,6,3,7]*4
  __shared__ __bf16 tile[64][72];
  const int bid = blockIdx.x;
  const int tk = bid & 63;
  const int tn = bid >> 6;
  const int k0 = tk * 64;
  const int c0 = tn * 8;
  const int t = threadIdx.x;
#pragma unroll
  for (int r = 0; r < 2; ++r) {
    int idx = r * 256 + t;
    int kk = idx >> 3;
    int cc = idx & 7;
    int k = k0 + kk;
    int c = c0 + cc;
    uint32_t q  = (uint32_t)qw[(size_t)k * NCOL + c];
    int g = k >> 7;
    uint32_t zq = (uint32_t)qz[(size_t)g * NCOL + c];
    const float* s = sc + (size_t)g * N_DIM + (size_t)c * 8;
#pragma unroll
    for (int j = 0; j < 8; ++j) {
      int wv = (int)((q >> SH[j]) & 15u) - (int)((zq >> SH[j]) & 15u);
      tile[cc * 8 + j][kk] = (__bf16)((float)wv * s[j]);
    }
  }
  __syncthreads();
  const int n0 = tn * 64;
#pragma unroll
  for (int r = 0; r < 2; ++r) {
    int idx = r * 256 + t;
    int row = idx >> 3;
    int kc = idx & 7;
    bf16x8 v = *(const bf16x8*)&tile[row][kc * 8];
    *(bf16x8*)(wt + (size_t)(n0 + row) * K_DIM + k0 + kc * 8) = v;
  }
}

// ---------- main GEMM: 128x128 tile, BK=64, A in LDS / B streamed from L2 ----------
// R7 post-mortem: throughput saturates at 43% MfmaUtil independent of resident
// blocks (2-4/CU identical) -> shared per-CU wall. Arithmetic: 96 KB LDS
// traffic per K-tile (64 read + 32 write) = 70 B/cy at 942 TF vs ~85 B/cy
// ds_read_b128 pipe (m134) = 82% -> LDS pipe is the wall.
// Fix: B panel (1 MB/block, L2/L3-resident, reused 16x across m-blocks) is
// streamed straight to registers; its frag pattern is line-coalesced (lanes
// l,l+16,l+32,l+48 cover 64 contiguous bytes per row -> 16x64B lines/load).
// LDS traffic drops to 48 KB/K-tile (A only, 35 B/cy).
// A keeps gload_lds + granule-XOR swizzle (0 conflicts R1-R7).
__global__ void __launch_bounds__(256, 3) wq_gemm_kernel(
    const __bf16* __restrict__ A,    // [M][K] bf16
    const __bf16* __restrict__ Wt,   // [N][K] bf16
    const float* __restrict__ bias,
    float* __restrict__ out,
    const int Mblk)
{
  __shared__ char As[16384];   // 128 rows x 64 bf16 (128B rows), granule-swizzled

  const int nwg = gridDim.x;
  int bid = blockIdx.x;
  if ((nwg & 7) == 0) {                 // XCD-aware swizzle (1376 % 8 == 0, bijective)
    const int cpx = nwg >> 3;
    bid = (bid & 7) * cpx + (bid >> 3);
  }
  const int bm = bid % Mblk;            // m-fastest: XCD chunk reuses B panels in L2
  const int bn = bid / Mblk;
  const int m0 = bm * 128;
  const int n0 = bn * 128;

  const int t = threadIdx.x;
  const int lane = t & 63;
  const int w = t >> 6;      // 0..3
  const int wr = w >> 1;     // 0..1  (M half)
  const int wc = w & 1;      // 0..1  (N half)
  const int lrow = lane & 15;
  const int lk = lane >> 4;

  // A staging: round i, cid = i*256+t; rp = cid>>3, gl = (cid&7)^(rp&7); dest linear
  const int gl = (t & 7) ^ ((t >> 3) & 7);
  const uint32_t off0 = (uint32_t)(t >> 3) * K_DIM + (uint32_t)gl * 8;
  const __bf16* pA = A + (size_t)m0 * K_DIM + off0;
  const int w1024 = w * 1024;

  // B streaming base: this lane serves rows {n0 + wc*64 + n*16 + lrow}, k-chunk lk*8
  const __bf16* pB = Wt + (size_t)(n0 + wc * 64 + lrow) * K_DIM + lk * 8;

  f32x4 acc[4][4];
#pragma unroll
  for (int i = 0; i < 4; ++i)
#pragma unroll
    for (int j = 0; j < 4; ++j) acc[i][j] = (f32x4){0.f, 0.f, 0.f, 0.f};

  // compute-side A base (row&7 == lrow&7 since frag row strides are multiples of 16)
  const char* abase = As + (wr * 64 + lrow) * 128;
  const int gk0 = (lk ^ (lrow & 7)) << 4;        // kk=0 granule byte offset
  const int gk1 = ((4 + lk) ^ (lrow & 7)) << 4;  // kk=1

  for (int kt = 0; kt < 64; ++kt) {
    __syncthreads();   // previous tile's A-reads done; As reusable
#pragma unroll
    for (int i = 0; i < 4; ++i)    // A: 4 DMA rounds (rows 32i .. 32i+31)
      gload_lds16(pA + (size_t)i * (32 * K_DIM), As + i * 4096 + w1024);
    pA += 64;
    // B fragments straight from global (L2-hot); issued here so their latency
    // hides under the staging barrier + ds_reads.
    bf16x8 bv[4][2];
#pragma unroll
    for (int n = 0; n < 4; ++n) {
      bv[n][0] = *(const bf16x8*)(pB + (size_t)n * (16 * K_DIM));
      bv[n][1] = *(const bf16x8*)(pB + (size_t)n * (16 * K_DIM) + 32);
    }
    pB += 64;
    __syncthreads();   // A-DMA visible (vmcnt counts B too; worst case = old drain)

#pragma unroll
    for (int kk = 0; kk < 2; ++kk) {
      const int g = kk ? gk1 : gk0;
      bf16x8 av[4];
#pragma unroll
      for (int m = 0; m < 4; ++m) av[m] = *(const bf16x8*)(abase + m * 2048 + g);
#pragma unroll
      for (int m = 0; m < 4; ++m)
#pragma unroll
        for (int n = 0; n < 4; ++n)
          acc[m][n] = __builtin_amdgcn_mfma_f32_16x16x32_bf16(av[m], bv[n][kk], acc[m][n], 0, 0, 0);
    }
  }

  // epilogue: C/D layout col=lane&15, row=(lane>>4)*4+reg (m89-verified, R1-R7-passed)
  const int orow0 = m0 + wr * 64 + lk * 4;
  const int ocol0 = n0 + wc * 64 + lrow;
#pragma unroll
  for (int n = 0; n < 4; ++n) {
    const int col = ocol0 + n * 16;
    const float bv = bias[col];
#pragma unroll
    for (int m = 0; m < 4; ++m) {
      float* po = out + (size_t)(orow0 + m * 16) * N_DIM + col;
      po[0]                 = acc[m][n][0] + bv;
      po[(size_t)N_DIM]     = acc[m][n][1] + bv;
      po[2 * (size_t)N_DIM] = acc[m][n][2] + bv;
      po[3 * (size_t)N_DIM] = acc[m][n][3] + bv;
    }
  }
}

extern "C" void kernel_launch(void* const* d_in, const int* in_sizes, int n_in,
                              void* d_out, int out_size, void* d_ws, size_t ws_size,
                              hipStream_t stream) {
  const float* x    = (const float*)d_in[0];
  const int* qw     = (const int*)d_in[1];
  const int* qz     = (const int*)d_in[2];
  const float* sc   = (const float*)d_in[3];
  const float* bias = (const float*)d_in[4];
  float* out = (float*)d_out;

  const int M = in_sizes[0] / K_DIM;        // 2048
  const int Mblk = M / 128;                 // 16
  const int grid = Mblk * (N_DIM / 128);    // 1376 (divisible by 8)

  const size_t abytes = (size_t)M * K_DIM * 2;
  __bf16* Aw = (__bf16*)d_ws;
  __bf16* Wt = (__bf16*)((char*)d_ws + abytes);

  convert_x_kernel<<<(M * K_DIM) / 2048, 256, 0, stream>>>(x, Aw);
  dequant_kernel<<<(K_DIM / 64) * (N_DIM / 64), 256, 0, stream>>>(qw, qz, sc, Wt);

  wq_gemm_kernel<<<grid, 256, 0, stream>>>(Aw, Wt, bias, out, Mblk);
}

// Round 9
// 234.232 us; speedup vs baseline: 1.8708x; 1.8708x over previous
//
#include <hip/hip_runtime.h>
#include <stdint.h>

#define K_DIM 4096
#define N_DIM 11008
#define NCOL  1376   // N/8

typedef __attribute__((ext_vector_type(4))) float  f32x4;
typedef __attribute__((ext_vector_type(8))) __bf16 bf16x8;

__device__ __forceinline__ void gload_lds16(const void* g, void* l) {
  __builtin_amdgcn_global_load_lds((const __attribute__((address_space(1))) void*)g,
                                   (__attribute__((address_space(3))) void*)l,
                                   16, 0, 0);
}

// ---------- prologue 1: x fp32 -> bf16 ----------
__global__ void __launch_bounds__(256) convert_x_kernel(const float* __restrict__ x,
                                                        __bf16* __restrict__ a) {
  size_t i = ((size_t)blockIdx.x * 256u + threadIdx.x) * 8u;
  f32x4 v0 = *(const f32x4*)(x + i);
  f32x4 v1 = *(const f32x4*)(x + i + 4);
  bf16x8 o;
  o[0] = (__bf16)v0[0]; o[1] = (__bf16)v0[1]; o[2] = (__bf16)v0[2]; o[3] = (__bf16)v0[3];
  o[4] = (__bf16)v1[0]; o[5] = (__bf16)v1[1]; o[6] = (__bf16)v1[2]; o[7] = (__bf16)v1[3];
  *(bf16x8*)(a + i) = o;
}

// ---------- prologue 2: AWQ dequant -> Wt bf16 [N][K] (transposed via LDS) ----------
__global__ void __launch_bounds__(256) dequant_kernel(const int* __restrict__ qw,
                                                      const int* __restrict__ qz,
                                                      const float* __restrict__ sc,
                                                      __bf16* __restrict__ wt) {
  constexpr int SH[8] = {0, 16, 4, 20, 8, 24, 12, 28};  // AWQ [0,4,1,5,2,6,3,7]*4
  __shared__ __bf16 tile[64][72];
  const int bid = blockIdx.x;
  const int tk = bid & 63;
  const int tn = bid >> 6;
  const int k0 = tk * 64;
  const int c0 = tn * 8;
  const int t = threadIdx.x;
#pragma unroll
  for (int r = 0; r < 2; ++r) {
    int idx = r * 256 + t;
    int kk = idx >> 3;
    int cc = idx & 7;
    int k = k0 + kk;
    int c = c0 + cc;
    uint32_t q  = (uint32_t)qw[(size_t)k * NCOL + c];
    int g = k >> 7;
    uint32_t zq = (uint32_t)qz[(size_t)g * NCOL + c];
    const float* s = sc + (size_t)g * N_DIM + (size_t)c * 8;
#pragma unroll
    for (int j = 0; j < 8; ++j) {
      int wv = (int)((q >> SH[j]) & 15u) - (int)((zq >> SH[j]) & 15u);
      tile[cc * 8 + j][kk] = (__bf16)((float)wv * s[j]);
    }
  }
  __syncthreads();
  const int n0 = tn * 64;
#pragma unroll
  for (int r = 0; r < 2; ++r) {
    int idx = r * 256 + t;
    int row = idx >> 3;
    int kc = idx & 7;
    bf16x8 v = *(const bf16x8*)&tile[row][kc * 8];
    *(bf16x8*)(wt + (size_t)(n0 + row) * K_DIM + k0 + kc * 8) = v;
  }
}

// ---------- main GEMM: 128(M) x 256(N) tile, BK=64, 2-barrier loop ----------
// 8 waves (512 thr) as 2M x 4N, per-wave 64x64 = 4x4 frags of 16x16x32 MFMA
// (identical per-wave workload to R1/R7, which measured 43% busy).
// Change vs R7: one stage+barrier pair now covers 4.19 MFLOP (2x R1) ->
// barrier/drain events per FLOP halved. LDS 48KB single-buffer; regs ~124
// -> 4 waves/SIMD -> 2 blocks/CU = 16 waves/CU (same hiding regime as R1).
// Grid 16x43 = 688: per-CU 2.69 blocks -> eff 0.896.
// Granule-XOR swizzle (0 conflicts R1-R8): row r, granule g at physical
// g^(r&7); linear gload dest + inverse-swizzled global source (rule #21).
__global__ void __launch_bounds__(512, 4) wq_gemm_kernel(
    const __bf16* __restrict__ A,    // [M][K] bf16
    const __bf16* __restrict__ Wt,   // [N][K] bf16
    const float* __restrict__ bias,
    float* __restrict__ out,
    const int Mblk)
{
  __shared__ char As[16384];   // 128 rows x 64 bf16 (128B rows)
  __shared__ char Bs[32768];   // 256 rows x 64 bf16

  const int nwg = gridDim.x;
  int bid = blockIdx.x;
  if ((nwg & 7) == 0) {                 // XCD-aware swizzle (688 % 8 == 0, bijective)
    const int cpx = nwg >> 3;
    bid = (bid & 7) * cpx + (bid >> 3);
  }
  const int bm = bid % Mblk;            // m-fastest: XCD chunk reuses B panels in L2
  const int bn = bid / Mblk;
  const int m0 = bm * 128;
  const int n0 = bn * 256;

  const int t = threadIdx.x;   // 0..511
  const int lane = t & 63;
  const int w = t >> 6;        // 0..7
  const int wm = w >> 2;       // 0..1  (M half)
  const int wn = w & 3;        // 0..3  (N quarter)
  const int lrow = lane & 15;
  const int lk = lane >> 4;

  // staging: round i, cid = i*512+t; rp = cid>>3 = i*64 + (t>>3);
  // gl = (cid&7)^(rp&7) = (t&7)^((t>>3)&7)  (i-independent); dest = cid*16 linear
  const int gl = (t & 7) ^ ((t >> 3) & 7);
  const uint32_t off0 = (uint32_t)(t >> 3) * K_DIM + (uint32_t)gl * 8;
  const __bf16* pA = A  + (size_t)m0 * K_DIM + off0;
  const __bf16* pB = Wt + (size_t)n0 * K_DIM + off0;
  const int dst = t * 16;      // per-round LDS dest (wave-uniform base + lane*16)

  f32x4 acc[4][4];
#pragma unroll
  for (int i = 0; i < 4; ++i)
#pragma unroll
    for (int j = 0; j < 4; ++j) acc[i][j] = (f32x4){0.f, 0.f, 0.f, 0.f};

  // compute-side bases (row&7 == lrow&7 since frag row strides are multiples of 16)
  const char* abase = As + (wm * 64 + lrow) * 128;
  const char* bbase = Bs + (wn * 64 + lrow) * 128;
  const int gk0 = (lk ^ (lrow & 7)) << 4;        // kk=0 granule byte offset
  const int gk1 = ((4 + lk) ^ (lrow & 7)) << 4;  // kk=1

  for (int kt = 0; kt < 64; ++kt) {
    __syncthreads();   // previous tile's compute done; LDS reusable
    // A: 2 rounds of 8KB (rows 64i .. 64i+63)
    gload_lds16(pA,                         As + dst);
    gload_lds16(pA + (size_t)(64 * K_DIM),  As + 8192 + dst);
    // B: 4 rounds of 8KB
#pragma unroll
    for (int i = 0; i < 4; ++i)
      gload_lds16(pB + (size_t)i * (64 * K_DIM), Bs + i * 8192 + dst);
    pA += 64; pB += 64;
    __syncthreads();   // compiler drains vmcnt(0): staged tile visible

#pragma unroll
    for (int kk = 0; kk < 2; ++kk) {
      const int g = kk ? gk1 : gk0;
      bf16x8 av[4], bv[4];
#pragma unroll
      for (int m = 0; m < 4; ++m) av[m] = *(const bf16x8*)(abase + m * 2048 + g);
#pragma unroll
      for (int n = 0; n < 4; ++n) bv[n] = *(const bf16x8*)(bbase + n * 2048 + g);
#pragma unroll
      for (int m = 0; m < 4; ++m)
#pragma unroll
        for (int n = 0; n < 4; ++n)
          acc[m][n] = __builtin_amdgcn_mfma_f32_16x16x32_bf16(av[m], bv[n], acc[m][n], 0, 0, 0);
    }
  }

  // epilogue: C/D layout col=lane&15, row=(lane>>4)*4+reg (m89-verified, R1-R8-passed)
  const int orow0 = m0 + wm * 64 + lk * 4;
  const int ocol0 = n0 + wn * 64 + lrow;
#pragma unroll
  for (int n = 0; n < 4; ++n) {
    const int col = ocol0 + n * 16;
    const float bv = bias[col];
#pragma unroll
    for (int m = 0; m < 4; ++m) {
      float* po = out + (size_t)(orow0 + m * 16) * N_DIM + col;
      po[0]                 = acc[m][n][0] + bv;
      po[(size_t)N_DIM]     = acc[m][n][1] + bv;
      po[2 * (size_t)N_DIM] = acc[m][n][2] + bv;
      po[3 * (size_t)N_DIM] = acc[m][n][3] + bv;
    }
  }
}

extern "C" void kernel_launch(void* const* d_in, const int* in_sizes, int n_in,
                              void* d_out, int out_size, void* d_ws, size_t ws_size,
                              hipStream_t stream) {
  const float* x    = (const float*)d_in[0];
  const int* qw     = (const int*)d_in[1];
  const int* qz     = (const int*)d_in[2];
  const float* sc   = (const float*)d_in[3];
  const float* bias = (const float*)d_in[4];
  float* out = (float*)d_out;

  const int M = in_sizes[0] / K_DIM;        // 2048
  const int Mblk = M / 128;                 // 16
  const int grid = Mblk * (N_DIM / 256);    // 16 * 43 = 688 (divisible by 8)

  const size_t abytes = (size_t)M * K_DIM * 2;
  __bf16* Aw = (__bf16*)d_ws;
  __bf16* Wt = (__bf16*)((char*)d_ws + abytes);

  convert_x_kernel<<<(M * K_DIM) / 2048, 256, 0, stream>>>(x, Aw);
  dequant_kernel<<<(K_DIM / 64) * (N_DIM / 64), 256, 0, stream>>>(qw, qz, sc, Wt);

  wq_gemm_kernel<<<grid, 512, 0, stream>>>(Aw, Wt, bias, out, Mblk);
}